// Round 1
// baseline (361.904 us; speedup 1.0000x reference)
//
#include <hip/hip_runtime.h>

// LengthAdaptor: B=16, T=512, C_IN=512, C_HID=256, C_EMB=384, K=5, MAX_DUR=8
// Outputs (concat, f32): x_up [16,4096,512] | ldp [16,512] | emb_up [16,4096,384]
//
// R10: fused conv+LN. Conv block = 8 waves, 32 rows x 256 cols (full LN row in
// one block): bias+leakyrelu+LayerNorm (+ final linear+mask for layer 2) run in
// the conv epilogue via shfl_xor row-reduce + small LDS cross-wave reduce.
// Removes both ln dispatches and the hraw f32 round-trip (5 -> 3 dispatches,
// -33.6MB HBM). Staging: issue-early/write-late (T14) double-buffered LDS,
// float4 loads, ONE barrier per K-chunk so HBM latency hides under MFMA.
// Conv/gather interleave (blk%3==0 -> conv) kept from R9.

constexpr int Bn = 16, Tn = 512, CIN1 = 512, CHID = 256, CEMB = 384, MAXMEL = 4096;
constexpr int NROWS = Bn * Tn;
#define LRELU 0.3f
#define EPSV 1e-5f

typedef __attribute__((ext_vector_type(8))) short bf16x8;
typedef __attribute__((ext_vector_type(4))) float f32x4;
typedef __attribute__((ext_vector_type(16))) float f32x16;
typedef __attribute__((ext_vector_type(4))) unsigned int u32x4;
typedef unsigned short ushort_t;

static __device__ __forceinline__ ushort_t f2bf(float f) {
  unsigned u = __builtin_bit_cast(unsigned, f);
  unsigned r = (u + 0x7fffu + ((u >> 16) & 1u)) >> 16;  // RNE
  return (ushort_t)r;
}

// ---------------------------------------------------------------------------
// Fused conv (32x32x16 MFMA) + bias + leakyrelu + LayerNorm [+ linear+mask].
// Block: 512 threads = 8 waves; tile 32 rows x 256 cols; wave nh owns cols
// nh*32..nh*32+31. A staged per 128-ci chunk in XOR-swizzled LDS, double
// buffered; B fragment-contiguous from L2 (layout produced by prep_kernel).
// ---------------------------------------------------------------------------
template <int CI, bool F32IN, bool FINAL>
static __device__ __forceinline__ void conv_ln_body(
    const int mt,
    const float* __restrict__ xin, const ushort_t* __restrict__ inbf,
    const ushort_t* __restrict__ wB,
    const float* __restrict__ bias, const float* __restrict__ g,
    const float* __restrict__ be, ushort_t* __restrict__ h1out,
    const float* __restrict__ lw, const float* __restrict__ lb,
    const unsigned char* __restrict__ mask, float* __restrict__ ldp) {
  constexpr int NCHUNK = CI / 128;
  constexpr int LDSTRIDE = 136;                 // 128 + 8 pad (ushorts)
  __shared__ ushort_t sA[2][36 * LDSTRIDE];     // 2 x 9792 B
  __shared__ float sred[32][8];
  __shared__ float s2red[32][8];
  __shared__ float smu[32];
  __shared__ float srs[32];

  const int b = mt >> 4, t0 = (mt & 15) * 32;
  const int tid = threadIdx.x;
  const int l = tid & 63, nh = tid >> 6;        // wave id 0..7 = col block
  const int lm = l & 31, lq = l >> 5;

  f32x16 acc;
#pragma unroll
  for (int i = 0; i < 16; ++i) acc[i] = 0.f;

  const ushort_t* pB = wB + (size_t)nh * 512 + l * 8;

  float4 rf[3];
  uint2 rb[3];

  // issue global loads for chunk (into regs) -- 1152 float4/uint2 units
  auto stage_load = [&](int chunk) {
    const int cibase = chunk * 128;
#pragma unroll
    for (int i = 0; i < 3; ++i) {
      const int p = i * 512 + tid;
      if (p < 1152) {
        const int r = p >> 5;
        const int t = t0 - 2 + r;
        if ((unsigned)t < (unsigned)Tn) {
          const size_t src = (size_t)(b * Tn + t) * CI + cibase + (p & 31) * 4;
          if constexpr (F32IN) rf[i] = *(const float4*)(xin + src);
          else                 rb[i] = *(const uint2*)(inbf + src);
        }
      }
    }
  };
  // convert + swizzled LDS write (after loads have had MFMA time to land)
  auto stage_write = [&](int bufi) {
    ushort_t* sa = sA[bufi];
#pragma unroll
    for (int i = 0; i < 3; ++i) {
      const int p = i * 512 + tid;
      if (p < 1152) {
        const int r = p >> 5, c4 = (p & 31) * 4;
        const int t = t0 - 2 + r;
        unsigned h0 = 0, h1v = 0;
        if ((unsigned)t < (unsigned)Tn) {
          if constexpr (F32IN) {
            h0  = (unsigned)f2bf(rf[i].x) | ((unsigned)f2bf(rf[i].y) << 16);
            h1v = (unsigned)f2bf(rf[i].z) | ((unsigned)f2bf(rf[i].w) << 16);
          } else {
            h0 = rb[i].x; h1v = rb[i].y;
          }
        }
        const int sw = ((r >> 3) & 3) << 3;
        uint2 u; u.x = h0; u.y = h1v;
        *(uint2*)&sa[r * LDSTRIDE + (c4 ^ sw)] = u;
      }
    }
  };
  auto mma_chunk = [&](int chunk, int bufi) {
    const ushort_t* sa = sA[bufi];
#pragma unroll 1
    for (int ksh = 0; ksh < 5; ++ksh) {
      const int r = lm + ksh;
      const int sw = ((r >> 3) & 3) << 3;
      const ushort_t* bp2 = pB + (size_t)((ksh * (CI / 16) + chunk * 8) * 8) * 512;
#pragma unroll
      for (int kk = 0; kk < 8; ++kk) {
        const int c = (kk * 16 + lq * 8) ^ sw;
        const bf16x8 a = *(const bf16x8*)&sa[r * LDSTRIDE + c];
        const bf16x8 bv = *(const bf16x8*)(bp2 + (size_t)kk * 8 * 512);
        acc = __builtin_amdgcn_mfma_f32_32x32x16_bf16(a, bv, acc, 0, 0, 0);
      }
    }
  };

  stage_load(0);
  stage_write(0);
#pragma unroll 1
  for (int c = 0; c < NCHUNK; ++c) {
    __syncthreads();                       // staged buf c&1 visible
    if (c + 1 < NCHUNK) stage_load(c + 1); // issue next loads (hide under MFMA)
    mma_chunk(c, c & 1);
    if (c + 1 < NCHUNK) stage_write((c + 1) & 1);
  }

  // ---- epilogue: bias + leakyrelu, then LN over 256 cols ----
  // D layout: col = nh*32 + (lane&31); row = (reg&3) + 8*(reg>>2) + 4*(lane>>5)
  const int col = nh * 32 + lm;
  const float bi = bias[col];
  float s[16], s2[16];
#pragma unroll
  for (int rg = 0; rg < 16; ++rg) {
    float xv = acc[rg] + bi;
    xv = (xv > 0.f) ? xv : LRELU * xv;
    acc[rg] = xv;
    s[rg] = xv;
    s2[rg] = xv * xv;
  }
  // reduce over the 32 cols this wave owns (stays inside 32-lane group)
#pragma unroll
  for (int off = 16; off >= 1; off >>= 1) {
#pragma unroll
    for (int rg = 0; rg < 16; ++rg) {
      s[rg]  += __shfl_xor(s[rg], off);
      s2[rg] += __shfl_xor(s2[rg], off);
    }
  }
  if (lm == 0) {
#pragma unroll
    for (int rg = 0; rg < 16; ++rg) {
      const int row = (rg & 3) + 8 * (rg >> 2) + 4 * lq;
      sred[row][nh] = s[rg];
      s2red[row][nh] = s2[rg];
    }
  }
  __syncthreads();
  if (tid < 32) {
    float a = 0.f, q = 0.f;
#pragma unroll
    for (int w = 0; w < 8; ++w) { a += sred[tid][w]; q += s2red[tid][w]; }
    const float mu = a * (1.f / 256.f);
    const float var = q * (1.f / 256.f) - mu * mu;
    smu[tid] = mu;
    srs[tid] = rsqrtf(var + EPSV);
  }
  __syncthreads();

  const float gc = g[col], bc = be[col];
  if constexpr (!FINAL) {
    ushort_t* po = h1out + (size_t)(b * Tn + t0) * 256 + col;
#pragma unroll
    for (int rg = 0; rg < 16; ++rg) {
      const int row = (rg & 3) + 8 * (rg >> 2) + 4 * lq;
      const float h = (acc[rg] - smu[row]) * srs[row] * gc + bc;
      po[(size_t)row * 256] = f2bf(h);
    }
  } else {
    const float wc = lw[col];
    float d[16];
#pragma unroll
    for (int rg = 0; rg < 16; ++rg) {
      const int row = (rg & 3) + 8 * (rg >> 2) + 4 * lq;
      const float h = (acc[rg] - smu[row]) * srs[row] * gc + bc;
      d[rg] = h * wc;
    }
#pragma unroll
    for (int off = 16; off >= 1; off >>= 1) {
#pragma unroll
      for (int rg = 0; rg < 16; ++rg) d[rg] += __shfl_xor(d[rg], off);
    }
    if (lm == 0) {
#pragma unroll
      for (int rg = 0; rg < 16; ++rg) {
        const int row = (rg & 3) + 8 * (rg >> 2) + 4 * lq;
        sred[row][nh] = d[rg];
      }
    }
    __syncthreads();
    if (tid < 32) {
      float a = lb[0];
#pragma unroll
      for (int w = 0; w < 8; ++w) a += sred[tid][w];
      const int grow = b * Tn + t0 + tid;
      ldp[grow] = mask[grow] ? 0.f : a;
    }
  }
}

// ---------------------------------------------------------------------------
// Dispatch 2: fused conv1+ln1 (blk%3==0, 256 blocks) + x_up gather (512 blk).
// ---------------------------------------------------------------------------
__global__ __launch_bounds__(512, 4) void conv1_fused_kernel(
    const float* __restrict__ x_res, const ushort_t* __restrict__ w1,
    const float* __restrict__ c1b, const float* __restrict__ g1,
    const float* __restrict__ b1, ushort_t* __restrict__ h1,
    const float* __restrict__ x, const int* __restrict__ idx,
    float* __restrict__ x_up) {
  const int blk = blockIdx.x;
  if (blk % 3 == 0) {
    conv_ln_body<512, true, false>(blk / 3, x_res, nullptr, w1, c1b, g1, b1, h1,
                                   nullptr, nullptr, nullptr, nullptr);
    return;
  }
  // ---- x_up gather: 512 blocks x 512 thr, 2,097,152 f32x4 units (8 iters) ----
  const int gid = blk - 1 - blk / 3;  // 0..511
  const f32x4* x4 = (const f32x4*)x;
  f32x4* xu4 = (f32x4*)x_up;
  const int tid0 = gid * 512 + threadIdx.x;
  const int stride = 512 * 512;
  const f32x4 z = (f32x4){0.f, 0.f, 0.f, 0.f};
  for (int u = tid0; u < Bn * MAXMEL * 128; u += stride) {
    const int bp = u >> 7, i = u & 127;
    const int t = idx[bp];
    const int b = bp >> 12;
    const f32x4 v = (t >= 0) ? x4[((b << 9) + t) * 128 + i] : z;
    __builtin_nontemporal_store(v, &xu4[u]);
  }
}

// ---------------------------------------------------------------------------
// Dispatch 3: fused conv2+ln2+linear+mask (256 blocks) + emb_up gather (512).
// ---------------------------------------------------------------------------
__global__ __launch_bounds__(512, 4) void conv2_fused_kernel(
    const ushort_t* __restrict__ h1, const ushort_t* __restrict__ w2,
    const float* __restrict__ c2b, const float* __restrict__ g2,
    const float* __restrict__ b2, const float* __restrict__ lw,
    const float* __restrict__ lb, const unsigned char* __restrict__ mask,
    float* __restrict__ ldp,
    const float* __restrict__ emb, const int* __restrict__ idx,
    float* __restrict__ emb_up) {
  const int blk = blockIdx.x;
  if (blk % 3 == 0) {
    conv_ln_body<256, false, true>(blk / 3, nullptr, h1, w2, c2b, g2, b2,
                                   nullptr, lw, lb, mask, ldp);
    return;
  }
  // ---- emb_up gather: 512 blocks x 512 thr, 1,572,864 f32x4 units (6 iters) ----
  const int gid = blk - 1 - blk / 3;
  const f32x4* e4 = (const f32x4*)emb;
  f32x4* eu4 = (f32x4*)emb_up;
  const int tid0 = gid * 512 + threadIdx.x;
  const int stride = 512 * 512;
  const f32x4 z = (f32x4){0.f, 0.f, 0.f, 0.f};
  for (int u = tid0; u < Bn * MAXMEL * 96; u += stride) {
    const int bp = u / 96, i = u - bp * 96;
    const int t = idx[bp];
    const int b = bp >> 12;
    const f32x4 v = (t >= 0) ? e4[((b << 9) + t) * 96 + i] : z;
    __builtin_nontemporal_store(v, &eu4[u]);
  }
}

// ---------------------------------------------------------------------------
// Dispatch 1: weight prep (blocks 0..239, 8 frags/block) + build_idx
// (blocks 240..255). 512 threads. (unchanged from R9)
// ---------------------------------------------------------------------------
__global__ __launch_bounds__(512) void prep_kernel(
    const float* __restrict__ w1src, const float* __restrict__ w2src,
    ushort_t* __restrict__ w1dst, ushort_t* __restrict__ w2dst,
    const int* __restrict__ dur, int* __restrict__ idx) {
  __shared__ int wsum[8];
  const int blk = blockIdx.x;
  const int tid = threadIdx.x;
  if (blk < 240) {
    const float* src;
    ushort_t* dst;
    int CI, fr, sh;
    const int wv = tid >> 6, l = tid & 63;
    if (blk < 160) { src = w1src; dst = w1dst; CI = 512; sh = 5; fr = blk * 8 + wv; }
    else           { src = w2src; dst = w2dst; CI = 256; sh = 4; fr = (blk - 160) * 8 + wv; }
    const int cob32 = fr & 7;
    const int t = fr >> 3;
    const int ksh = t >> sh;
    const int ci16 = t & ((1 << sh) - 1);
    const int ci = ci16 * 16 + (l >> 5) * 8;
    const int co = cob32 * 32 + (l & 31);
    ushort_t v[8];
#pragma unroll
    for (int j = 0; j < 8; ++j)
      v[j] = f2bf(src[((size_t)(ksh * CI + ci + j)) * 256 + co]);
    u32x4 pack;
#pragma unroll
    for (int q = 0; q < 4; ++q)
      pack[q] = (unsigned)v[q * 2] | ((unsigned)v[q * 2 + 1] << 16);
    *(u32x4*)&dst[(size_t)fr * 512 + l * 8] = pack;
    return;
  }
  // ---- build_idx path ----
  const int b = blk - 240;
  const int lane = tid & 63, wv = tid >> 6;
  const int d = dur[b * Tn + tid];
  int v = d;
#pragma unroll
  for (int off = 1; off <= 32; off <<= 1) {
    const int t = __shfl_up(v, off);
    if (lane >= off) v += t;
  }
  if (lane == 63) wsum[wv] = v;
  __syncthreads();
  int woff = 0, total = 0;
#pragma unroll
  for (int i = 0; i < 8; ++i) {
    const int s = wsum[i];
    if (i < wv) woff += s;
    total += s;
  }
  const int end = v + woff;               // inclusive cumsum
  for (int p = end - d; p < end; ++p) idx[b * MAXMEL + p] = tid;
  for (int p = total + tid; p < MAXMEL; p += 512) idx[b * MAXMEL + p] = -1;
}

// ---------------------------------------------------------------------------
extern "C" void kernel_launch(void* const* d_in, const int* in_sizes, int n_in,
                              void* d_out, int out_size, void* d_ws, size_t ws_size,
                              hipStream_t stream) {
  const float* x     = (const float*)d_in[0];
  const float* x_res = (const float*)d_in[1];
  const int*   dur   = (const int*)d_in[2];
  const float* emb   = (const float*)d_in[3];
  const unsigned char* mask = (const unsigned char*)d_in[4];
  const float* c1w = (const float*)d_in[5];
  const float* c1b = (const float*)d_in[6];
  const float* g1  = (const float*)d_in[7];
  const float* b1  = (const float*)d_in[8];
  const float* c2w = (const float*)d_in[9];
  const float* c2b = (const float*)d_in[10];
  const float* g2  = (const float*)d_in[11];
  const float* b2  = (const float*)d_in[12];
  const float* lw  = (const float*)d_in[13];
  const float* lb  = (const float*)d_in[14];

  float* x_up   = (float*)d_out;
  float* ldp    = x_up + (size_t)Bn * MAXMEL * CIN1;
  float* emb_up = ldp + (size_t)Bn * Tn;

  // ws layout: idx 256KB | h1 4MB | w1 1.31MB | w2 0.66MB  (~6.2MB)
  int* idx = (int*)d_ws;
  ushort_t* h1 = (ushort_t*)((char*)d_ws + (size_t)Bn * MAXMEL * 4);
  ushort_t* w1 = h1 + (size_t)NROWS * 256;
  ushort_t* w2 = w1 + (size_t)5 * 512 * 256;

  prep_kernel<<<256, 512, 0, stream>>>(c1w, c2w, w1, w2, dur, idx);
  conv1_fused_kernel<<<768, 512, 0, stream>>>(
      x_res, w1, c1b, g1, b1, h1, x, idx, x_up);
  conv2_fused_kernel<<<768, 512, 0, stream>>>(
      h1, w2, c2b, g2, b2, lw, lb, mask, ldp, emb, idx, emb_up);
}